// Round 5
// baseline (441.887 us; speedup 1.0000x reference)
//
#include <hip/hip_runtime.h>
#include <hip/hip_bf16.h>

// ParallelExperts: out = mean_e( relu(x@W1[e]+b1[e]) @ W2[e] + b2[e] ) @ Wf + bf
// Final linear folded past the expert-mean (one GEMM3 on ybar).
//
// GEMM1/GEMM2: 256x256 tile, BK=64, 8 waves, ring-2 LDS (2 x 64 KiB slots),
// counted-vmcnt pipeline: per iter { vmcnt(8); bar; compute(t); bar;
// stage(t+2) }. Each K-tile stored as two [256][32] half-tiles (64B rows)
// to avoid the 128B-row 16-way bank-conflict regime.
// GEMM3 (small, 8.6 GF): verified 128x128 m97-structure kernel.

#define D_IN  1024
#define D_HID 2048
#define D_OUT 1024
#define N_EXP 8
#define N_TOK 4096

typedef __attribute__((ext_vector_type(4))) float  f32x4;
typedef __attribute__((ext_vector_type(8))) short  s16x8;
typedef __attribute__((ext_vector_type(4))) short  s16x4;
typedef __attribute__((ext_vector_type(8))) __bf16 b16x8;

static __device__ __forceinline__ f32x4 mfma16x16x32(s16x8 a, s16x8 b, f32x4 c) {
  return __builtin_amdgcn_mfma_f32_16x16x32_bf16(
      __builtin_bit_cast(b16x8, a), __builtin_bit_cast(b16x8, b), c, 0, 0, 0);
}

#define GLDS16(gptr, lptr)                                                         \
  __builtin_amdgcn_global_load_lds(                                               \
      (const __attribute__((address_space(1))) void*)(gptr),                      \
      (__attribute__((address_space(3))) void*)(lptr), 16, 0, 0)

#define WAITV(n) asm volatile("s_waitcnt vmcnt(" #n ")" ::: "memory")
#define SBAR()                                                                     \
  do {                                                                             \
    __builtin_amdgcn_sched_barrier(0);                                             \
    __builtin_amdgcn_s_barrier();                                                  \
    __builtin_amdgcn_sched_barrier(0);                                             \
  } while (0)

static __device__ __forceinline__ short f2b(float f) {
  return __builtin_bit_cast(short, __float2bfloat16(f));
}
static __device__ __forceinline__ float b2f(short s) {
  return __bfloat162float(__builtin_bit_cast(__hip_bfloat16, s));
}

// ---------------- prep kernels ----------------

__global__ void cast_x_kernel(const float* __restrict__ in, short* __restrict__ out, int n4) {
  int i = blockIdx.x * blockDim.x + threadIdx.x;
  if (i >= n4) return;
  f32x4 v = ((const f32x4*)in)[i];
  s16x4 o;
  o[0] = f2b(v[0]); o[1] = f2b(v[1]); o[2] = f2b(v[2]); o[3] = f2b(v[3]);
  ((s16x4*)out)[i] = o;
}

// in: [R][C] f32 (slab z), out: [C][R] bf16 (slab z)
__global__ void tcast_kernel(const float* __restrict__ in, short* __restrict__ out, int R, int C) {
  __shared__ float t[32][33];
  size_t slab = (size_t)blockIdx.z * R * C;
  const float* src = in + slab;
  short* dst = out + slab;
  int c0 = blockIdx.x * 32, r0 = blockIdx.y * 32;
  int tx = threadIdx.x, ty = threadIdx.y;
#pragma unroll
  for (int i = 0; i < 32; i += 8)
    t[ty + i][tx] = src[(size_t)(r0 + ty + i) * C + c0 + tx];
  __syncthreads();
#pragma unroll
  for (int i = 0; i < 32; i += 8)
    dst[(size_t)(c0 + ty + i) * R + r0 + tx] = f2b(t[tx][ty + i]);
}

__global__ void b2mean_kernel(const float* __restrict__ b2, float* __restrict__ b2m) {
  int o = blockIdx.x * blockDim.x + threadIdx.x;
  if (o < D_OUT) {
    float s = 0.f;
#pragma unroll
    for (int e = 0; e < N_EXP; ++e) s += b2[e * D_OUT + o];
    b2m[o] = s * 0.125f;
  }
}

// ---------------- 256x256 ring-2 BK=64 GEMM ----------------
// C[M,N] = A[M,K] * Bt[N,K]^T (+bias[col]) (+relu), per blockIdx.z slab.
// 8 waves (2M x 4N), per-wave 128x64 output. LDS slot (64 KiB) layout:
//   A: [half ks(2)][256 rows][32 k] (16384 shorts), then B same.

template <bool RELU, bool OUTBF16>
__global__ __launch_bounds__(512) void gemm256_r2_kernel(
    const short* __restrict__ A, const short* __restrict__ Bt, void* __restrict__ C,
    const float* __restrict__ bias, int K, int ldc,
    long sAe, long sBe, long sCe, long sBiasE) {
  constexpr int BM = 256, BN = 256, BK = 64;
  constexpr int SLOT = 32768;            // shorts per ring slot (A 16384 + B 16384)
  extern __shared__ short lds[];         // 2 slots = 128 KiB

  const int tid  = threadIdx.x;
  const int wid  = tid >> 6;
  const int lane = tid & 63;
  const int e    = blockIdx.z;

  const short* Ab = A + (size_t)e * sAe + (size_t)blockIdx.y * BM * K;
  const short* Bb = Bt + (size_t)e * sBe + (size_t)blockIdx.x * BN * K;

  // staging: per (half h, region r): wave wid covers rows r*128+wid*16..+15;
  // lane -> row += lane>>2, k8 = lane&3. LDS dest wave-uniform; lane-linear
  // dest (base + lane*8 shorts) == (lane>>2)*32 + (lane&3)*8 by identity.
  const int strow = wid * 16 + (lane >> 2);
  const int stcol = (lane & 3) * 8;

  const int wm = wid >> 2, wn = wid & 3;            // 2M x 4N wave grid
  const int lr = lane & 15, lk = (lane >> 4) * 8;   // fragment lane geometry

  f32x4 acc[8][4] = {};
  const int nkt = K / BK;  // >= 16 for all our shapes

  auto STAGE = [&](int t) {
    short* slot = lds + (size_t)(t & 1) * SLOT;
    const size_t ko = (size_t)t * BK;
#pragma unroll
    for (int h = 0; h < 2; ++h)
#pragma unroll
      for (int r = 0; r < 2; ++r) {
        GLDS16(Ab + (size_t)(r * 128 + strow) * K + ko + h * 32 + stcol,
               slot + h * 8192 + (r * 128 + wid * 16) * 32);
        GLDS16(Bb + (size_t)(r * 128 + strow) * K + ko + h * 32 + stcol,
               slot + 16384 + h * 8192 + (r * 128 + wid * 16) * 32);
      }
  };

  auto COMPUTE = [&](int t) {
    const short* As_ = lds + (size_t)(t & 1) * SLOT;
    const short* Bs_ = As_ + 16384;
#pragma unroll
    for (int ks = 0; ks < 2; ++ks) {
      s16x8 av[8], bv[4];
#pragma unroll
      for (int mi = 0; mi < 8; ++mi)
        av[mi] = *(const s16x8*)&As_[ks * 8192 + (wm * 128 + mi * 16 + lr) * 32 + lk];
#pragma unroll
      for (int ni = 0; ni < 4; ++ni)
        bv[ni] = *(const s16x8*)&Bs_[ks * 8192 + (wn * 64 + ni * 16 + lr) * 32 + lk];
      __builtin_amdgcn_s_setprio(1);
#pragma unroll
      for (int mi = 0; mi < 8; ++mi)
#pragma unroll
        for (int ni = 0; ni < 4; ++ni)
          acc[mi][ni] = mfma16x16x32(av[mi], bv[ni], acc[mi][ni]);
      __builtin_amdgcn_s_setprio(0);
    }
  };

  // prologue: 2 tiles in flight (16 loads/thread)
  STAGE(0); STAGE(1);

  // main loop: vmcnt(8) certifies tile t landed (tile t+1's 8 loads stay in
  // flight); barrier makes it collective. stage(t+2) reuses slot t after the
  // post-compute barrier certifies all waves finished reading it.
  for (int t = 0; t < nkt - 1; ++t) {
    WAITV(8);
    SBAR();
    COMPUTE(t);
    SBAR();
    if (t + 2 < nkt) STAGE(t + 2);
  }
  // peeled last tile: drain fully
  WAITV(0);
  SBAR();
  COMPUTE(nkt - 1);

  // epilogue: D mapping col=lane&15, row=(lane>>4)*4+j
  const size_t Cbase = (size_t)e * sCe;
  const int row0 = blockIdx.y * BM + wm * 128 + (lane >> 4) * 4;
  const int col0 = blockIdx.x * BN + wn * 64 + lr;
#pragma unroll
  for (int ni = 0; ni < 4; ++ni) {
    const int col = col0 + ni * 16;
    const float bvv = bias ? bias[(size_t)e * sBiasE + col] : 0.f;
#pragma unroll
    for (int mi = 0; mi < 8; ++mi) {
#pragma unroll
      for (int j = 0; j < 4; ++j) {
        float v = acc[mi][ni][j] + bvv;
        if (RELU) v = v > 0.f ? v : 0.f;
        const size_t idx = Cbase + (size_t)(row0 + mi * 16 + j) * ldc + col;
        if (OUTBF16) ((short*)C)[idx] = f2b(v);
        else         ((float*)C)[idx] = v;
      }
    }
  }
}

// ---------------- 128x128 m97 GEMM (kept for GEMM3) ----------------

template <bool RELU, bool OUTBF16>
__global__ __launch_bounds__(256) void gemm_bt_kernel(
    const short* __restrict__ A, const short* __restrict__ Bt, void* __restrict__ C,
    const float* __restrict__ bias, int K, int ldc,
    long sAe, long sBe, long sCe, long sBiasE) {
  constexpr int BM = 128, BN = 128, BK = 32;
  __shared__ short As[BM * BK];
  __shared__ short Bs[BN * BK];
  const int tid  = threadIdx.x;
  const int wid  = tid >> 6;
  const int lane = tid & 63;
  const int e    = blockIdx.z;

  const short* Ap = A + (size_t)e * sAe + (size_t)blockIdx.y * BM * K;
  const short* Bp = Bt + (size_t)e * sBe + (size_t)blockIdx.x * BN * K;

  const int srow = wid * 16 + (lane >> 2);
  const int scol = (lane & 3) * 8;
  const int wm = (wid >> 1) * 64, wn = (wid & 1) * 64;
  const int lr = lane & 15, lk = (lane >> 4) * 8;

  f32x4 acc[4][4] = {};
  const int nkt = K / BK;
  for (int kt = 0; kt < nkt; ++kt) {
    __syncthreads();
    const size_t ko = (size_t)kt * BK;
    GLDS16(Ap + (size_t)srow * K + ko + scol,        &As[wid * 512]);
    GLDS16(Ap + (size_t)(srow + 64) * K + ko + scol, &As[2048 + wid * 512]);
    GLDS16(Bp + (size_t)srow * K + ko + scol,        &Bs[wid * 512]);
    GLDS16(Bp + (size_t)(srow + 64) * K + ko + scol, &Bs[2048 + wid * 512]);
    __syncthreads();

    s16x8 a[4], b[4];
#pragma unroll
    for (int mi = 0; mi < 4; ++mi)
      a[mi] = *(const s16x8*)&As[(wm + mi * 16 + lr) * BK + lk];
#pragma unroll
    for (int ni = 0; ni < 4; ++ni)
      b[ni] = *(const s16x8*)&Bs[(wn + ni * 16 + lr) * BK + lk];
#pragma unroll
    for (int mi = 0; mi < 4; ++mi)
#pragma unroll
      for (int ni = 0; ni < 4; ++ni)
        acc[mi][ni] = mfma16x16x32(a[mi], b[ni], acc[mi][ni]);
  }

  const size_t Cbase = (size_t)e * sCe;
  const int row0 = blockIdx.y * BM + wm + (lane >> 4) * 4;
  const int col0 = blockIdx.x * BN + wn + lr;
#pragma unroll
  for (int ni = 0; ni < 4; ++ni) {
    const int col = col0 + ni * 16;
    const float bv = bias ? bias[(size_t)e * sBiasE + col] : 0.f;
#pragma unroll
    for (int mi = 0; mi < 4; ++mi) {
#pragma unroll
      for (int j = 0; j < 4; ++j) {
        float v = acc[mi][ni][j] + bv;
        if (RELU) v = v > 0.f ? v : 0.f;
        const size_t idx = Cbase + (size_t)(row0 + mi * 16 + j) * ldc + col;
        if (OUTBF16) ((short*)C)[idx] = f2b(v);
        else         ((float*)C)[idx] = v;
      }
    }
  }
}

// ---------------- reduce over experts (per token-chunk) ----------------

__global__ void reduce_y_kernel(const short* __restrict__ yal, const float* __restrict__ b2m,
                                short* __restrict__ ybar, long slab, long total) {
  const size_t base = ((size_t)blockIdx.x * blockDim.x + threadIdx.x) * 8;
  if (base >= (size_t)total) return;
  float s[8] = {};
#pragma unroll
  for (int e = 0; e < N_EXP; ++e) {
    s16x8 v = *(const s16x8*)&yal[(size_t)e * slab + base];
#pragma unroll
    for (int j = 0; j < 8; ++j) s[j] += b2f(v[j]);
  }
  const int col = (int)(base & (D_OUT - 1));
  s16x8 o;
#pragma unroll
  for (int j = 0; j < 8; ++j) o[j] = f2b(s[j] * 0.125f + b2m[col + j]);
  *(s16x8*)&ybar[base] = o;
}

__global__ void tail_kernel(float* __restrict__ out, int from, int n) {
  int i = from + blockIdx.x * blockDim.x + threadIdx.x;
  if (i < n) out[i] = 0.f;
}

// ---------------- launch ----------------

extern "C" void kernel_launch(void* const* d_in, const int* in_sizes, int n_in,
                              void* d_out, int out_size, void* d_ws, size_t ws_size,
                              hipStream_t stream) {
  const float* x  = (const float*)d_in[0];
  const float* W1 = (const float*)d_in[1];
  const float* b1 = (const float*)d_in[2];
  const float* W2 = (const float*)d_in[3];
  const float* b2 = (const float*)d_in[4];
  const float* Wf = (const float*)d_in[5];
  const float* bf = (const float*)d_in[6];
  float* out = (float*)d_out;

  // ---- adaptive chunking: fit fixed + (h+yal)/NC into ws_size ----
  const size_t sz_xb  = (size_t)N_TOK * D_IN * 2;
  const size_t sz_W1t = (size_t)N_EXP * D_HID * D_IN * 2;
  const size_t sz_W2t = (size_t)N_EXP * D_OUT * D_HID * 2;
  const size_t sz_Wft = (size_t)D_OUT * D_OUT * 2;
  const size_t sz_b2m = (size_t)D_OUT * 4;
  const size_t sz_ybr = (size_t)N_TOK * D_OUT * 2;
  const size_t fixed  = sz_xb + sz_W1t + sz_W2t + sz_Wft + sz_b2m + sz_ybr;
  const size_t per_full = (size_t)N_EXP * N_TOK * D_HID * 2   // h
                        + (size_t)N_EXP * N_TOK * D_OUT * 2;  // yal
  int NC = 16;
  for (int c = 1; c <= 8; c <<= 1) {
    if (fixed + per_full / c <= ws_size) { NC = c; break; }
  }
  const int ntokc = N_TOK / NC;

  char* ws = (char*)d_ws;
  short* xb  = (short*)ws; ws += sz_xb;
  short* W1t = (short*)ws; ws += sz_W1t;
  short* W2t = (short*)ws; ws += sz_W2t;
  short* Wft = (short*)ws; ws += sz_Wft;
  float* b2m = (float*)ws; ws += sz_b2m;
  short* ybr = (short*)ws; ws += sz_ybr;
  short* h   = (short*)ws; ws += (size_t)N_EXP * ntokc * D_HID * 2;
  short* yal = (short*)ws;

  // ---- prep: casts + transposes ----
  hipLaunchKernelGGL(cast_x_kernel, dim3(N_TOK * D_IN / 4 / 256), dim3(256), 0, stream,
                     x, xb, N_TOK * D_IN / 4);
  hipLaunchKernelGGL(tcast_kernel, dim3(D_HID / 32, D_IN / 32, N_EXP), dim3(32, 8), 0, stream,
                     W1, W1t, D_IN, D_HID);
  hipLaunchKernelGGL(tcast_kernel, dim3(D_OUT / 32, D_HID / 32, N_EXP), dim3(32, 8), 0, stream,
                     W2, W2t, D_HID, D_OUT);
  hipLaunchKernelGGL(tcast_kernel, dim3(D_OUT / 32, D_OUT / 32, 1), dim3(32, 8), 0, stream,
                     Wf, Wft, D_OUT, D_OUT);
  hipLaunchKernelGGL(b2mean_kernel, dim3(4), dim3(256), 0, stream, b2, b2m);

  const size_t ldsz = 131072;  // 2-slot ring LDS (2 x 64 KiB)

  // ---- per-token-chunk: GEMM1 -> GEMM2 -> expert-mean ----
  for (int c = 0; c < NC; ++c) {
    const short* xc = xb + (size_t)c * ntokc * D_IN;
    short* ybc = ybr + (size_t)c * ntokc * D_OUT;

    // h[e] = relu(xc @ W1[e] + b1[e])   [ntokc, D_HID] per e
    hipLaunchKernelGGL((gemm256_r2_kernel<true, true>),
                       dim3(D_HID / 256, ntokc / 256, N_EXP), dim3(512), ldsz, stream,
                       xc, W1t, (void*)h, b1, D_IN, D_HID,
                       0L, (long)D_HID * D_IN, (long)ntokc * D_HID, (long)D_HID);

    // yal[e] = h[e] @ W2[e]   [ntokc, D_OUT] per e (bias folded into reduce)
    hipLaunchKernelGGL((gemm256_r2_kernel<false, true>),
                       dim3(D_OUT / 256, ntokc / 256, N_EXP), dim3(512), ldsz, stream,
                       h, W2t, (void*)yal, (const float*)nullptr, D_HID, D_OUT,
                       (long)ntokc * D_HID, (long)D_OUT * D_HID, (long)ntokc * D_OUT, 0L);

    // ybc = mean_e yal + mean_e b2
    hipLaunchKernelGGL(reduce_y_kernel, dim3(ntokc * D_OUT / 8 / 256), dim3(256), 0, stream,
                       yal, b2m, ybc, (long)ntokc * D_OUT, (long)ntokc * D_OUT);
  }

  // ---- out = ybar @ Wf + bf  (fp32 out), 128^2 kernel ----
  hipLaunchKernelGGL((gemm_bt_kernel<false, false>),
                     dim3(D_OUT / 128, N_TOK / 128, 1), dim3(256), 0, stream,
                     ybr, Wft, d_out, bf, D_OUT, D_OUT, 0L, 0L, 0L, 0L);

  // ---- second (scalar) output = 0 ----
  int tail = out_size - N_TOK * D_OUT;
  if (tail > 0)
    hipLaunchKernelGGL(tail_kernel, dim3((tail + 63) / 64), dim3(64), 0, stream,
                       out, N_TOK * D_OUT, out_size);
}

// Round 6
// 364.982 us; speedup vs baseline: 1.2107x; 1.2107x over previous
//
#include <hip/hip_runtime.h>
#include <hip/hip_bf16.h>

// ParallelExperts: out = mean_e( relu(x@W1[e]+b1[e]) @ W2[e] + b2[e] ) @ Wf + bf
// Final linear folded past the expert-mean (one GEMM3 on ybar).
//
// GEMM1/GEMM2: 256x256 tile, BK=64, 8 waves, 8-phase schedule (T2+T3+T4+T5):
//  - per phase: [vmcnt(8) even] stage 1 half-tile; ds_read next quadrant's
//    frags; s_barrier; 16 MFMA under setprio(1).
//  - LDS: 2 bufs x {A,B} x {ks0,ks1} [256][32] half-blocks (128 KiB), XOR
//    swizzle g_p = g_l ^ ((row>>1)&3) -> 2-way (free) bank profile; swizzle
//    applied via pre-swizzled global source (per-thread constant).
//  - C epilogue staged through LDS -> coalesced 16B stores.
// GEMM3 (small, 8.6 GF): verified 128x128 m97-structure kernel.

#define D_IN  1024
#define D_HID 2048
#define D_OUT 1024
#define N_EXP 8
#define N_TOK 4096

typedef __attribute__((ext_vector_type(4))) float  f32x4;
typedef __attribute__((ext_vector_type(8))) short  s16x8;
typedef __attribute__((ext_vector_type(4))) short  s16x4;
typedef __attribute__((ext_vector_type(8))) __bf16 b16x8;

static __device__ __forceinline__ f32x4 mfma16x16x32(s16x8 a, s16x8 b, f32x4 c) {
  return __builtin_amdgcn_mfma_f32_16x16x32_bf16(
      __builtin_bit_cast(b16x8, a), __builtin_bit_cast(b16x8, b), c, 0, 0, 0);
}

#define GLDS16(gptr, lptr)                                                         \
  __builtin_amdgcn_global_load_lds(                                               \
      (const __attribute__((address_space(1))) void*)(gptr),                      \
      (__attribute__((address_space(3))) void*)(lptr), 16, 0, 0)

#define WAITV(n) asm volatile("s_waitcnt vmcnt(" #n ")" ::: "memory")
#define SBAR()                                                                     \
  do {                                                                             \
    __builtin_amdgcn_sched_barrier(0);                                             \
    __builtin_amdgcn_s_barrier();                                                  \
    __builtin_amdgcn_sched_barrier(0);                                             \
  } while (0)

static __device__ __forceinline__ short f2b(float f) {
  return __builtin_bit_cast(short, __float2bfloat16(f));
}
static __device__ __forceinline__ float b2f(short s) {
  return __bfloat162float(__builtin_bit_cast(__hip_bfloat16, s));
}

// ---------------- prep kernels ----------------

__global__ void cast_x_kernel(const float* __restrict__ in, short* __restrict__ out, int n4) {
  int i = blockIdx.x * blockDim.x + threadIdx.x;
  if (i >= n4) return;
  f32x4 v = ((const f32x4*)in)[i];
  s16x4 o;
  o[0] = f2b(v[0]); o[1] = f2b(v[1]); o[2] = f2b(v[2]); o[3] = f2b(v[3]);
  ((s16x4*)out)[i] = o;
}

// in: [R][C] f32 (slab z), out: [C][R] bf16 (slab z)
__global__ void tcast_kernel(const float* __restrict__ in, short* __restrict__ out, int R, int C) {
  __shared__ float t[32][33];
  size_t slab = (size_t)blockIdx.z * R * C;
  const float* src = in + slab;
  short* dst = out + slab;
  int c0 = blockIdx.x * 32, r0 = blockIdx.y * 32;
  int tx = threadIdx.x, ty = threadIdx.y;
#pragma unroll
  for (int i = 0; i < 32; i += 8)
    t[ty + i][tx] = src[(size_t)(r0 + ty + i) * C + c0 + tx];
  __syncthreads();
#pragma unroll
  for (int i = 0; i < 32; i += 8)
    dst[(size_t)(c0 + ty + i) * R + r0 + tx] = f2b(t[tx][ty + i]);
}

__global__ void b2mean_kernel(const float* __restrict__ b2, float* __restrict__ b2m) {
  int o = blockIdx.x * blockDim.x + threadIdx.x;
  if (o < D_OUT) {
    float s = 0.f;
#pragma unroll
    for (int e = 0; e < N_EXP; ++e) s += b2[e * D_OUT + o];
    b2m[o] = s * 0.125f;
  }
}

// ---------------- 256x256 8-phase GEMM (T2+T3+T4+T5) ----------------
// C[M,N] = A[M,K] * Bt[N,K]^T (+bias[col]) (+relu, bf16 out), per blockIdx.z.
// LDS (shorts): buf(t&1)*32768 + AB*16384 + ks*8192 ; half-block [256][32].

template <bool RELU>
__global__ __launch_bounds__(512, 2) void gemm256_p8_kernel(
    const short* __restrict__ A, const short* __restrict__ Bt,
    short* __restrict__ C, const float* __restrict__ bias,
    int K, int ldc, long sAe, long sBe, long sCe, long sBiasE) {
  extern __shared__ short lds[];  // 65536 shorts = 128 KiB
  const int tid = threadIdx.x, wid = tid >> 6, lane = tid & 63;
  const int e = blockIdx.z;
  const short* Ab = A + (size_t)e * sAe + (size_t)blockIdx.y * 256 * K;
  const short* Bb = Bt + (size_t)e * sBe + (size_t)blockIdx.x * 256 * K;

  // staging geometry: thread covers row strow (+128 for 2nd load), 8 shorts.
  // source col pre-swizzled so linear LDS dest holds swizzled layout (T2).
  const int strow = wid * 16 + (lane >> 2);
  const int stcol = ((lane & 3) ^ ((strow >> 1) & 3)) * 8;
  const int wm = wid >> 2, wn = wid & 3;  // 2M x 4N wave grid
  const int lr = lane & 15;
  const int gp = ((lane >> 4) ^ ((lr >> 1) & 3)) * 8;  // swizzled read group

  f32x4 acc[8][4] = {};
  const int nkt = K / 64;
  const int niter = nkt / 2;

  auto SLOT = [&](int t, int ks, int ab) -> short* {
    return lds + (size_t)(t & 1) * 32768 + ab * 16384 + ks * 8192;
  };
  auto STAGE = [&](int t, int ks, int ab) {  // one half-tile = 2 gload_lds
    const short* src = ab ? Bb : Ab;
    short* dst = SLOT(t, ks, ab) + wid * 512;
    const size_t ko = (size_t)t * 64 + ks * 32 + stcol;
    GLDS16(src + (size_t)strow * K + ko, dst);
    GLDS16(src + (size_t)(128 + strow) * K + ko, dst + 4096);
  };
  auto LDA = [&](s16x8* av, int t, int h, int ks) {
    const short* s = SLOT(t, ks, 0);
#pragma unroll
    for (int m = 0; m < 4; ++m)
      av[m] = *(const s16x8*)&s[(wm * 128 + h * 64 + m * 16 + lr) * 32 + gp];
  };
  auto LDB = [&](s16x8* bv, int t, int ks) {
    const short* s = SLOT(t, ks, 1);
#pragma unroll
    for (int n = 0; n < 4; ++n)
      bv[n] = *(const s16x8*)&s[(wn * 64 + n * 16 + lr) * 32 + gp];
  };
  auto QUAD = [&](int h, const s16x8* av, const s16x8* bv) {
    __builtin_amdgcn_s_setprio(1);
#pragma unroll
    for (int m = 0; m < 4; ++m)
#pragma unroll
      for (int n = 0; n < 4; ++n)
        acc[h * 4 + m][n] = mfma16x16x32(av[m], bv[n], acc[h * 4 + m][n]);
    __builtin_amdgcn_s_setprio(0);
  };

  s16x8 av0[4], av1[4], bv0[4], bv1[4];

  // prologue: 7 half-tiles (t0 complete, t1 ks0 A/B, t1 ks1 A)
  STAGE(0, 0, 0); STAGE(0, 0, 1); STAGE(0, 1, 0); STAGE(0, 1, 1);
  STAGE(1, 0, 0); STAGE(1, 0, 1); STAGE(1, 1, 0);
  WAITV(10);  // certify t0 ks0 A,B
  SBAR();
  LDA(av1, 0, 0, 0);
  LDB(bv0, 0, 0);

  // main: phase p computes quadrant p, reads frags for p+1, stages 1 ht.
  // vmcnt(8) at even-phase START certifies the slot read this phase.
  for (int i = 0; i < niter - 1; ++i) {
    const int t0 = 2 * i, t1 = t0 + 1;
    /*p1*/ STAGE(t1, 1, 1); LDA(av0, t0, 1, 0);
           SBAR(); QUAD(0, av1, bv0);
    /*p2*/ WAITV(8); STAGE(t0 + 2, 0, 0); LDA(av1, t0, 0, 1); LDB(bv1, t0, 1);
           SBAR(); QUAD(1, av0, bv0);
    /*p3*/ STAGE(t0 + 2, 0, 1); LDA(av0, t0, 1, 1);
           SBAR(); QUAD(0, av1, bv1);
    /*p4*/ WAITV(8); STAGE(t0 + 2, 1, 0); LDA(av1, t1, 0, 0); LDB(bv0, t1, 0);
           SBAR(); QUAD(1, av0, bv1);
    /*p5*/ STAGE(t0 + 2, 1, 1); LDA(av0, t1, 1, 0);
           SBAR(); QUAD(0, av1, bv0);
    /*p6*/ WAITV(8); STAGE(t0 + 3, 0, 0); LDA(av1, t1, 0, 1); LDB(bv1, t1, 1);
           SBAR(); QUAD(1, av0, bv0);
    /*p7*/ STAGE(t0 + 3, 0, 1); LDA(av0, t1, 1, 1);
           SBAR(); QUAD(0, av1, bv1);
    /*p8*/ WAITV(8); STAGE(t0 + 3, 1, 0); LDA(av1, t0 + 2, 0, 0); LDB(bv0, t0 + 2, 0);
           SBAR(); QUAD(1, av0, bv1);
  }
  {  // last iteration: only t1's final half-tile staged; drain 8 -> 0
    const int t0 = nkt - 2, t1 = nkt - 1;
    /*p1*/ STAGE(t1, 1, 1); LDA(av0, t0, 1, 0);
           SBAR(); QUAD(0, av1, bv0);
    /*p2*/ WAITV(8); LDA(av1, t0, 0, 1); LDB(bv1, t0, 1);
           SBAR(); QUAD(1, av0, bv0);
    /*p3*/ LDA(av0, t0, 1, 1);
           SBAR(); QUAD(0, av1, bv1);
    /*p4*/ WAITV(0); LDA(av1, t1, 0, 0); LDB(bv0, t1, 0);
           SBAR(); QUAD(1, av0, bv1);
    /*p5*/ LDA(av0, t1, 1, 0);
           SBAR(); QUAD(0, av1, bv0);
    /*p6*/ LDA(av1, t1, 0, 1); LDB(bv1, t1, 1);
           SBAR(); QUAD(1, av0, bv0);
    /*p7*/ LDA(av0, t1, 1, 1);
           SBAR(); QUAD(0, av1, bv1);
    /*p8*/ SBAR(); QUAD(1, av0, bv1);
  }

  // epilogue: acc -> LDS C tile [256][256] -> coalesced 16B global stores
  __syncthreads();
  const int crow0 = wm * 128 + (lane >> 4) * 4;
  const int ccol0 = wn * 64 + lr;
#pragma unroll
  for (int ni = 0; ni < 4; ++ni) {
    const int col = ccol0 + ni * 16;
    const float bvv =
        bias ? bias[(size_t)e * sBiasE + (size_t)blockIdx.x * 256 + col] : 0.f;
#pragma unroll
    for (int mi = 0; mi < 8; ++mi)
#pragma unroll
      for (int j = 0; j < 4; ++j) {
        float v = acc[mi][ni][j] + bvv;
        if (RELU) v = v > 0.f ? v : 0.f;
        lds[(crow0 + mi * 16 + j) * 256 + col] = f2b(v);
      }
  }
  __syncthreads();
  short* Cp = C + (size_t)e * sCe + (size_t)blockIdx.y * 256 * ldc +
              (size_t)blockIdx.x * 256;
  const int cr = tid >> 5, cc = (tid & 31) * 8;
#pragma unroll
  for (int r = 0; r < 256; r += 16) {
    s16x8 v = *(const s16x8*)&lds[(r + cr) * 256 + cc];
    *(s16x8*)&Cp[(size_t)(r + cr) * ldc + cc] = v;
  }
}

// ---------------- 128x128 m97 GEMM (kept for GEMM3) ----------------

template <bool RELU, bool OUTBF16>
__global__ __launch_bounds__(256) void gemm_bt_kernel(
    const short* __restrict__ A, const short* __restrict__ Bt, void* __restrict__ C,
    const float* __restrict__ bias, int K, int ldc,
    long sAe, long sBe, long sCe, long sBiasE) {
  constexpr int BM = 128, BN = 128, BK = 32;
  __shared__ short As[BM * BK];
  __shared__ short Bs[BN * BK];
  const int tid  = threadIdx.x;
  const int wid  = tid >> 6;
  const int lane = tid & 63;
  const int e    = blockIdx.z;

  const short* Ap = A + (size_t)e * sAe + (size_t)blockIdx.y * BM * K;
  const short* Bp = Bt + (size_t)e * sBe + (size_t)blockIdx.x * BN * K;

  const int srow = wid * 16 + (lane >> 2);
  const int scol = (lane & 3) * 8;
  const int wm = (wid >> 1) * 64, wn = (wid & 1) * 64;
  const int lr = lane & 15, lk = (lane >> 4) * 8;

  f32x4 acc[4][4] = {};
  const int nkt = K / BK;
  for (int kt = 0; kt < nkt; ++kt) {
    __syncthreads();
    const size_t ko = (size_t)kt * BK;
    GLDS16(Ap + (size_t)srow * K + ko + scol,        &As[wid * 512]);
    GLDS16(Ap + (size_t)(srow + 64) * K + ko + scol, &As[2048 + wid * 512]);
    GLDS16(Bp + (size_t)srow * K + ko + scol,        &Bs[wid * 512]);
    GLDS16(Bp + (size_t)(srow + 64) * K + ko + scol, &Bs[2048 + wid * 512]);
    __syncthreads();

    s16x8 a[4], b[4];
#pragma unroll
    for (int mi = 0; mi < 4; ++mi)
      a[mi] = *(const s16x8*)&As[(wm + mi * 16 + lr) * BK + lk];
#pragma unroll
    for (int ni = 0; ni < 4; ++ni)
      b[ni] = *(const s16x8*)&Bs[(wn + ni * 16 + lr) * BK + lk];
#pragma unroll
    for (int mi = 0; mi < 4; ++mi)
#pragma unroll
      for (int ni = 0; ni < 4; ++ni)
        acc[mi][ni] = mfma16x16x32(a[mi], b[ni], acc[mi][ni]);
  }

  const size_t Cbase = (size_t)e * sCe;
  const int row0 = blockIdx.y * BM + wm + (lane >> 4) * 4;
  const int col0 = blockIdx.x * BN + wn + lr;
#pragma unroll
  for (int ni = 0; ni < 4; ++ni) {
    const int col = col0 + ni * 16;
    const float bv = bias ? bias[(size_t)e * sBiasE + col] : 0.f;
#pragma unroll
    for (int mi = 0; mi < 4; ++mi) {
#pragma unroll
      for (int j = 0; j < 4; ++j) {
        float v = acc[mi][ni][j] + bv;
        if (RELU) v = v > 0.f ? v : 0.f;
        const size_t idx = Cbase + (size_t)(row0 + mi * 16 + j) * ldc + col;
        if (OUTBF16) ((short*)C)[idx] = f2b(v);
        else         ((float*)C)[idx] = v;
      }
    }
  }
}

// ---------------- reduce over experts (per token-chunk) ----------------

__global__ void reduce_y_kernel(const short* __restrict__ yal, const float* __restrict__ b2m,
                                short* __restrict__ ybar, long slab, long total) {
  const size_t base = ((size_t)blockIdx.x * blockDim.x + threadIdx.x) * 8;
  if (base >= (size_t)total) return;
  float s[8] = {};
#pragma unroll
  for (int e = 0; e < N_EXP; ++e) {
    s16x8 v = *(const s16x8*)&yal[(size_t)e * slab + base];
#pragma unroll
    for (int j = 0; j < 8; ++j) s[j] += b2f(v[j]);
  }
  const int col = (int)(base & (D_OUT - 1));
  s16x8 o;
#pragma unroll
  for (int j = 0; j < 8; ++j) o[j] = f2b(s[j] * 0.125f + b2m[col + j]);
  *(s16x8*)&ybar[base] = o;
}

__global__ void tail_kernel(float* __restrict__ out, int from, int n) {
  int i = from + blockIdx.x * blockDim.x + threadIdx.x;
  if (i < n) out[i] = 0.f;
}

// ---------------- launch ----------------

extern "C" void kernel_launch(void* const* d_in, const int* in_sizes, int n_in,
                              void* d_out, int out_size, void* d_ws, size_t ws_size,
                              hipStream_t stream) {
  const float* x  = (const float*)d_in[0];
  const float* W1 = (const float*)d_in[1];
  const float* b1 = (const float*)d_in[2];
  const float* W2 = (const float*)d_in[3];
  const float* b2 = (const float*)d_in[4];
  const float* Wf = (const float*)d_in[5];
  const float* bf = (const float*)d_in[6];
  float* out = (float*)d_out;

  // ---- adaptive chunking: fit fixed + (h+yal)/NC into ws_size ----
  const size_t sz_xb  = (size_t)N_TOK * D_IN * 2;
  const size_t sz_W1t = (size_t)N_EXP * D_HID * D_IN * 2;
  const size_t sz_W2t = (size_t)N_EXP * D_OUT * D_HID * 2;
  const size_t sz_Wft = (size_t)D_OUT * D_OUT * 2;
  const size_t sz_b2m = (size_t)D_OUT * 4;
  const size_t sz_ybr = (size_t)N_TOK * D_OUT * 2;
  const size_t fixed  = sz_xb + sz_W1t + sz_W2t + sz_Wft + sz_b2m + sz_ybr;
  const size_t per_full = (size_t)N_EXP * N_TOK * D_HID * 2   // h
                        + (size_t)N_EXP * N_TOK * D_OUT * 2;  // yal
  int NC = 16;
  for (int c = 1; c <= 8; c <<= 1) {
    if (fixed + per_full / c <= ws_size) { NC = c; break; }
  }
  const int ntokc = N_TOK / NC;

  char* ws = (char*)d_ws;
  short* xb  = (short*)ws; ws += sz_xb;
  short* W1t = (short*)ws; ws += sz_W1t;
  short* W2t = (short*)ws; ws += sz_W2t;
  short* Wft = (short*)ws; ws += sz_Wft;
  float* b2m = (float*)ws; ws += sz_b2m;
  short* ybr = (short*)ws; ws += sz_ybr;
  short* h   = (short*)ws; ws += (size_t)N_EXP * ntokc * D_HID * 2;
  short* yal = (short*)ws;

  // ---- prep: casts + transposes ----
  hipLaunchKernelGGL(cast_x_kernel, dim3(N_TOK * D_IN / 4 / 256), dim3(256), 0, stream,
                     x, xb, N_TOK * D_IN / 4);
  hipLaunchKernelGGL(tcast_kernel, dim3(D_HID / 32, D_IN / 32, N_EXP), dim3(32, 8), 0, stream,
                     W1, W1t, D_IN, D_HID);
  hipLaunchKernelGGL(tcast_kernel, dim3(D_OUT / 32, D_HID / 32, N_EXP), dim3(32, 8), 0, stream,
                     W2, W2t, D_HID, D_OUT);
  hipLaunchKernelGGL(tcast_kernel, dim3(D_OUT / 32, D_OUT / 32, 1), dim3(32, 8), 0, stream,
                     Wf, Wft, D_OUT, D_OUT);
  hipLaunchKernelGGL(b2mean_kernel, dim3(4), dim3(256), 0, stream, b2, b2m);

  const size_t ldsz = 131072;  // 128 KiB (dbuf tiles; reused for C staging)

  // ---- per-token-chunk: GEMM1 -> GEMM2 -> expert-mean ----
  for (int c = 0; c < NC; ++c) {
    const short* xc = xb + (size_t)c * ntokc * D_IN;
    short* ybc = ybr + (size_t)c * ntokc * D_OUT;

    // h[e] = relu(xc @ W1[e] + b1[e])   [ntokc, D_HID] per e
    hipLaunchKernelGGL((gemm256_p8_kernel<true>),
                       dim3(D_HID / 256, ntokc / 256, N_EXP), dim3(512), ldsz, stream,
                       xc, W1t, h, b1, D_IN, D_HID,
                       0L, (long)D_HID * D_IN, (long)ntokc * D_HID, (long)D_HID);

    // yal[e] = h[e] @ W2[e]   [ntokc, D_OUT] per e (bias folded into reduce)
    hipLaunchKernelGGL((gemm256_p8_kernel<false>),
                       dim3(D_OUT / 256, ntokc / 256, N_EXP), dim3(512), ldsz, stream,
                       h, W2t, yal, (const float*)nullptr, D_HID, D_OUT,
                       (long)ntokc * D_HID, (long)D_OUT * D_HID, (long)ntokc * D_OUT, 0L);

    // ybc = mean_e yal + mean_e b2
    hipLaunchKernelGGL(reduce_y_kernel, dim3(ntokc * D_OUT / 8 / 256), dim3(256), 0, stream,
                       yal, b2m, ybc, (long)ntokc * D_OUT, (long)ntokc * D_OUT);
  }

  // ---- out = ybar @ Wf + bf  (fp32 out), 128^2 kernel ----
  hipLaunchKernelGGL((gemm_bt_kernel<false, false>),
                     dim3(D_OUT / 128, N_TOK / 128, 1), dim3(256), 0, stream,
                     ybr, Wft, d_out, bf, D_OUT, D_OUT, 0L, 0L, 0L, 0L);

  // ---- second (scalar) output = 0 ----
  int tail = out_size - N_TOK * D_OUT;
  if (tail > 0)
    hipLaunchKernelGGL(tail_kernel, dim3((tail + 63) / 64), dim3(64), 0, stream,
                       out, N_TOK * D_OUT, out_size);
}